// Round 7
// baseline (276.254 us; speedup 1.0000x reference)
//
#include <hip/hip_runtime.h>
#include <hip/hip_bf16.h>

typedef _Float16 half8v __attribute__((ext_vector_type(8)));
typedef __fp16  fp16x2 __attribute__((ext_vector_type(2)));   // cvt_pkrtz return type
typedef float floatx4 __attribute__((ext_vector_type(4)));

#define NB 32
#define NT 2048
#define ND 1024
#define NM (NB * NT)

// global->LDS direct DMA, 16B per lane. Linear LDS dest; swizzle on the
// GLOBAL source address (rule #21).
#define GL16(g, l)                                                             \
    __builtin_amdgcn_global_load_lds(                                          \
        (const __attribute__((address_space(1))) void*)(g),                    \
        (__attribute__((address_space(3))) void*)(l), 16, 0, 0)

__device__ __forceinline__ float fast_tanh(float x) {
    x = fminf(9.0f, fmaxf(-9.0f, x));
    float e = __builtin_amdgcn_exp2f(x * 2.8853900817779268f); // e^(2x)
    return (e - 1.0f) * __builtin_amdgcn_rcpf(e + 1.0f);
}

// ---------------- W [K][N] f32  ->  Wt [N][K] fp16 ----------------
__global__ __launch_bounds__(256)
void wt_kernel(const float* __restrict__ W, _Float16* __restrict__ Wt) {
    __shared__ float tile[32][33];
    int tx = threadIdx.x, ty = threadIdx.y;
    int bx = blockIdx.x, by = blockIdx.y;
    #pragma unroll
    for (int i = 0; i < 4; ++i) {
        int y = by * 32 + ty + i * 8;
        tile[ty + i * 8][tx] = W[y * ND + bx * 32 + tx];
    }
    __syncthreads();
    #pragma unroll
    for (int i = 0; i < 4; ++i) {
        int e = bx * 32 + ty + i * 8;
        Wt[e * ND + by * 32 + tx] = (_Float16)tile[tx][ty + i * 8];
    }
}

// ---------------- many f32 -> manyh fp16 (streaming, RTN) ----------------
__global__ __launch_bounds__(256)
void conv_kernel(const float* __restrict__ many, _Float16* __restrict__ manyh) {
    size_t idx = ((size_t)blockIdx.x * 256 + threadIdx.x) * 8;
    size_t stride = (size_t)gridDim.x * 256 * 8;
    for (size_t i = idx; i < (size_t)NM * ND; i += stride) {
        float4 a = *reinterpret_cast<const float4*>(many + i);
        float4 b = *reinterpret_cast<const float4*>(many + i + 4);
        union { _Float16 h[8]; uint4 u; } o;
        o.h[0] = (_Float16)a.x; o.h[1] = (_Float16)a.y;
        o.h[2] = (_Float16)a.z; o.h[3] = (_Float16)a.w;
        o.h[4] = (_Float16)b.x; o.h[5] = (_Float16)b.y;
        o.h[6] = (_Float16)b.z; o.h[7] = (_Float16)b.w;
        *reinterpret_cast<uint4*>(manyh + i) = o.u;
    }
}

// ---- 10-slot deep-pipelined GEMM + tanh + dot(one) -> logits (fp16) -------
// BM=BN=256, BK=64, 512 thr (8 waves 2Mx4N, wave-out 128x64).
// LDS 160 KiB = 10 slots x 16 KiB. Unit u (= 4*ktile + r, r: 0=A-half0,
// 1=A-half1, 2=B-half0, 3=B-half1) lives in slot u%10. Per phase stage ONE
// unit at lookahead 6..9 (u = 4t+6+q); boundary vmcnt(4) retires through
// unit 4t+7 (all of tile t+1) with 3-6 phases of latency cover. Slot-overwrite
// audit: writes at tile t hit slots 4t+{6..9} mod 10, replacing units last
// read at tile t-1 (>=2 barriers earlier); reads at t,t+1 touch 4t+{0..7}. Safe.
__global__ __launch_bounds__(512, 2)
void gemm_logits_10s(const _Float16* __restrict__ manyh, const _Float16* __restrict__ Wt,
                     const float* __restrict__ one, float* __restrict__ logits) {
    __shared__ uint4 LDSQ[10240];         // 160 KiB
    char* Ld = (char*)LDSQ;

    int bid = blockIdx.x;                  // 1024 blocks
    int j = (bid & 7) * 128 + (bid >> 3);  // XCD-chunked, bijective
    int mb = j >> 2, nb = j & 3;
    int m0 = mb * 256, n0 = nb * 256;

    int tid = threadIdx.x;
    int lane = tid & 63, w = tid >> 6;
    int wr = w >> 2, wc = w & 3;           // 2 M-halves x 4 N-quarters
    int l15 = lane & 15, l4 = lane >> 4;

    // staging: thread -> row tid>>3 (0..63 within a 64-row group), chunk tid&7;
    // source chunk ^= row&7 (row mod 8 invariant under +64/+128 row offsets)
    const char* aS = (const char*)manyh + ((size_t)(m0 + (tid >> 3)) << 11)
                   + (size_t)(((tid & 7) ^ ((tid >> 3) & 7)) << 4);
    const char* bS = (const char*)Wt + ((size_t)(n0 + (tid >> 3)) << 11)
                   + (size_t)(((tid & 7) ^ ((tid >> 3) & 7)) << 4);
    int ldst = tid * 16;

#define SUNIT(u) do {                                                          \
        int r_ = (u) & 3, tt_ = (u) >> 2, sl_ = (u) % 10;                      \
        const char* s_ = ((r_ >> 1) ? bS : aS) + ((size_t)(r_ & 1) << 18)      \
                         + ((size_t)tt_ << 7);                                 \
        char* d_ = Ld + sl_ * 16384 + ldst;                                    \
        GL16(s_, d_);                                                          \
        GL16(s_ + (64u << 11), d_ + 8192);                                     \
    } while (0)

    floatx4 acc[8][4] = {};
    int key = l15 & 7;
    int lof0 = l15 * 128 + (((0 | l4) ^ key) << 4);   // kk=0 chunk
    int lof1 = l15 * 128 + (((4 | l4) ^ key) << 4);   // kk=1 chunk

    // prologue: units 0..5 (tile0 complete + tile1 A-halves), allow units 4,5
    #pragma unroll
    for (int u = 0; u < 6; ++u) SUNIT(u);
    asm volatile("s_waitcnt vmcnt(4)" ::: "memory");
    __builtin_amdgcn_sched_barrier(0);
    __builtin_amdgcn_s_barrier();

    half8v af[4][2], b0f[2][2], b1f[2][2];

    #pragma unroll 1
    for (int t = 0; t < 16; ++t) {
        int t4 = t * 4;
        const char* ab = Ld + ((t4 + wr) % 10) * 16384;
        const char* bb = Ld + ((t4 + 2 + (wc >> 1)) % 10) * 16384 + ((wc & 1) << 13);

        // phase Q: C-quadrant (qm=Q>>1, qn=Q&1) x K=64; frag reuse across phases
#define PHASE(Q) do {                                                          \
        constexpr int qm_ = (Q) >> 1;                                          \
        if ((Q) == 0 || (Q) == 2) {                                            \
            _Pragma("unroll")                                                  \
            for (int mi = 0; mi < 4; ++mi) {                                   \
                af[mi][0] = *(const half8v*)(ab + (qm_ << 13) + (mi << 11) + lof0); \
                af[mi][1] = *(const half8v*)(ab + (qm_ << 13) + (mi << 11) + lof1); \
            }                                                                  \
        }                                                                      \
        if ((Q) == 0) {                                                        \
            _Pragma("unroll")                                                  \
            for (int ni = 0; ni < 2; ++ni) {                                   \
                b0f[ni][0] = *(const half8v*)(bb + (ni << 11) + lof0);         \
                b0f[ni][1] = *(const half8v*)(bb + (ni << 11) + lof1);         \
            }                                                                  \
        }                                                                      \
        if ((Q) == 1) {                                                        \
            _Pragma("unroll")                                                  \
            for (int ni = 0; ni < 2; ++ni) {                                   \
                b1f[ni][0] = *(const half8v*)(bb + 4096 + (ni << 11) + lof0);  \
                b1f[ni][1] = *(const half8v*)(bb + 4096 + (ni << 11) + lof1);  \
            }                                                                  \
        }                                                                      \
        { int u_ = t4 + 6 + (Q); if (u_ <= 63) SUNIT(u_); }                    \
        __builtin_amdgcn_s_barrier();                                          \
        __builtin_amdgcn_s_setprio(1);                                         \
        _Pragma("unroll")                                                      \
        for (int kk = 0; kk < 2; ++kk)                                         \
            _Pragma("unroll")                                                  \
            for (int mi = 0; mi < 4; ++mi)                                     \
                _Pragma("unroll")                                              \
                for (int ni = 0; ni < 2; ++ni)                                 \
                    acc[qm_ * 4 + mi][((Q) & 1) * 2 + ni] =                    \
                        __builtin_amdgcn_mfma_f32_16x16x32_f16(                \
                            af[mi][kk], ((Q) & 1) ? b1f[ni][kk] : b0f[ni][kk], \
                            acc[qm_ * 4 + mi][((Q) & 1) * 2 + ni], 0, 0, 0);   \
        __builtin_amdgcn_s_setprio(0);                                         \
    } while (0)

        PHASE(0);
        __builtin_amdgcn_s_barrier();
        PHASE(1);
        __builtin_amdgcn_s_barrier();
        PHASE(2);
        __builtin_amdgcn_s_barrier();
        PHASE(3);
        if (t <= 13)      asm volatile("s_waitcnt vmcnt(4)" ::: "memory");
        else if (t == 14) asm volatile("s_waitcnt vmcnt(0)" ::: "memory");
        __builtin_amdgcn_sched_barrier(0);
        __builtin_amdgcn_s_barrier();
#undef PHASE
    }
#undef SUNIT

    // epilogue: tanh * one, reduce over 16 col-lanes, atomicAdd logits
    int bidx = m0 >> 11;
    float onev[4];
    #pragma unroll
    for (int ni = 0; ni < 4; ++ni)
        onev[ni] = one[(bidx << 10) + n0 + wc * 64 + ni * 16 + l15];

    #pragma unroll
    for (int mi = 0; mi < 8; ++mi) {
        float part[4] = {0.f, 0.f, 0.f, 0.f};
        #pragma unroll
        for (int ni = 0; ni < 4; ++ni)
            #pragma unroll
            for (int b = 0; b < 4; ++b)
                part[b] += fast_tanh(acc[mi][ni][b]) * onev[ni];
        #pragma unroll
        for (int off = 1; off < 16; off <<= 1)
            #pragma unroll
            for (int b = 0; b < 4; ++b)
                part[b] += __shfl_xor(part[b], off, 64);
        #pragma unroll
        for (int b = 0; b < 4; ++b)
            if (l15 == ((mi * 4 + b) & 15))
                atomicAdd(&logits[m0 + wr * 128 + mi * 16 + l4 * 4 + b], part[b]);
    }
}

// ---------------- fallback GEMM (A f32 from global, cvt at frag read) ------
__global__ __launch_bounds__(256, 2)
void gemm_logits(const float* __restrict__ many, const _Float16* __restrict__ Wt,
                 const float* __restrict__ one, float* __restrict__ logits) {
    __shared__ uint4 AsQ[2048];
    __shared__ uint4 BsQ[1024];
    char* AsB = (char*)AsQ;
    char* BsB = (char*)BsQ;

    int bid = blockIdx.x;
    int j = (bid & 7) * 512 + (bid >> 3);
    int mb = j >> 3, nb = j & 7;
    int m0 = mb * 128, n0 = nb * 128;

    int tid = threadIdx.x;
    int lane = tid & 63, w = tid >> 6;
    int wr = w >> 1, wc = w & 1;
    int l15 = lane & 15, l4 = lane >> 4;

    const char* aS = (const char*)many + ((size_t)(m0 + (tid >> 4)) << 12)
        + (size_t)(((tid & 15) ^ ((tid >> 4) & 7)) << 4);
    const char* bS = (const char*)Wt + ((size_t)(n0 + (tid >> 3)) << 11)
        + (size_t)(((tid & 7) ^ ((tid >> 3) & 7)) << 4);
    char* aD = AsB + tid * 16;
    char* bD = BsB + tid * 16;

    floatx4 acc[4][4] = {};

    for (int kb = 0; kb < 1024; kb += 64) {
        #pragma unroll
        for (int i = 0; i < 8; ++i)
            GL16(aS + kb * 4 + i * 65536, aD + i * 4096);
        #pragma unroll
        for (int i = 0; i < 4; ++i)
            GL16(bS + kb * 2 + i * 65536, bD + i * 4096);
        __syncthreads();

        #pragma unroll
        for (int ks = 0; ks < 64; ks += 32) {
            half8v af[4], bf[4];
            #pragma unroll
            for (int mi = 0; mi < 4; ++mi) {
                int r = wr * 64 + mi * 16 + l15;
                int s = l15 & 7;
                const char* base = AsB + r * 256;
                int c0 = (ks >> 2) + l4 * 2;
                float4 x = *(const float4*)(base + (size_t)((c0 ^ s) << 4));
                float4 y = *(const float4*)(base + (size_t)(((c0 + 1) ^ s) << 4));
                union { fp16x2 p[4]; half8v h; } u;
                u.p[0] = __builtin_amdgcn_cvt_pkrtz(x.x, x.y);
                u.p[1] = __builtin_amdgcn_cvt_pkrtz(x.z, x.w);
                u.p[2] = __builtin_amdgcn_cvt_pkrtz(y.x, y.y);
                u.p[3] = __builtin_amdgcn_cvt_pkrtz(y.z, y.w);
                af[mi] = u.h;
            }
            #pragma unroll
            for (int ni = 0; ni < 4; ++ni) {
                int r = wc * 64 + ni * 16 + l15;
                int s = l15 & 7;
                int c = (ks >> 3) + l4;
                bf[ni] = *(const half8v*)(BsB + r * 128 + (size_t)((c ^ s) << 4));
            }
            #pragma unroll
            for (int mi = 0; mi < 4; ++mi)
                #pragma unroll
                for (int ni = 0; ni < 4; ++ni)
                    acc[mi][ni] = __builtin_amdgcn_mfma_f32_16x16x32_f16(
                        af[mi], bf[ni], acc[mi][ni], 0, 0, 0);
        }
        __syncthreads();
    }

    int bidx = m0 >> 11;
    float onev[4];
    #pragma unroll
    for (int ni = 0; ni < 4; ++ni)
        onev[ni] = one[(bidx << 10) + n0 + wc * 64 + ni * 16 + l15];

    #pragma unroll
    for (int mi = 0; mi < 4; ++mi) {
        float part[4] = {0.f, 0.f, 0.f, 0.f};
        #pragma unroll
        for (int ni = 0; ni < 4; ++ni)
            #pragma unroll
            for (int b = 0; b < 4; ++b)
                part[b] += fast_tanh(acc[mi][ni][b]) * onev[ni];
        #pragma unroll
        for (int off = 1; off < 16; off <<= 1)
            #pragma unroll
            for (int b = 0; b < 4; ++b)
                part[b] += __shfl_xor(part[b], off, 64);
        #pragma unroll
        for (int b = 0; b < 4; ++b)
            if (l15 == mi * 4 + b)
                atomicAdd(&logits[m0 + wr * 64 + mi * 16 + l4 * 4 + b], part[b]);
    }
}

// ---------------- softmax over T per batch ----------------
__global__ __launch_bounds__(256)
void softmax_kernel(const float* __restrict__ logits, float* __restrict__ att) {
    int b = blockIdx.x, tid = threadIdx.x;
    const float* lr = logits + (b << 11);
    float lv[8];
    float mx = -1e30f;
    #pragma unroll
    for (int i = 0; i < 8; ++i) { lv[i] = lr[tid + (i << 8)]; mx = fmaxf(mx, lv[i]); }
    #pragma unroll
    for (int off = 1; off < 64; off <<= 1) mx = fmaxf(mx, __shfl_xor(mx, off, 64));
    __shared__ float redm[4];
    __shared__ float reds[4];
    int wv = tid >> 6;
    if ((tid & 63) == 0) redm[wv] = mx;
    __syncthreads();
    mx = fmaxf(fmaxf(redm[0], redm[1]), fmaxf(redm[2], redm[3]));
    float s = 0.f;
    #pragma unroll
    for (int i = 0; i < 8; ++i) { lv[i] = expf(lv[i] - mx); s += lv[i]; }
    #pragma unroll
    for (int off = 1; off < 64; off <<= 1) s += __shfl_xor(s, off, 64);
    if ((tid & 63) == 0) reds[wv] = s;
    __syncthreads();
    s = reds[0] + reds[1] + reds[2] + reds[3];
    float inv = 1.0f / (s + 1e-7f);
    #pragma unroll
    for (int i = 0; i < 8; ++i) att[(b << 11) + tid + (i << 8)] = lv[i] * inv;
}

// ------- result[b][d] = sum_t many[b][t][d] * att[b][t] (fp16 input) -------
__global__ __launch_bounds__(256)
void out_kernel_h(const _Float16* __restrict__ manyh, const float* __restrict__ att,
                  float* __restrict__ out) {
    int b = blockIdx.x >> 4, tch = blockIdx.x & 15;
    int tid = threadIdx.x;
    __shared__ float aw[128];
    if (tid < 128) aw[tid] = att[(b << 11) + tch * 128 + tid];
    __syncthreads();
    const _Float16* mp = manyh + (((size_t)b * NT + tch * 128) << 10) + tid * 4;
    float a0 = 0.f, a1 = 0.f, a2 = 0.f, a3 = 0.f;
    for (int t = 0; t < 128; ++t) {
        float wgt = aw[t];
        union { _Float16 h[4]; uint2 u; } v;
        v.u = *reinterpret_cast<const uint2*>(mp + ((size_t)t << 10));
        a0 = fmaf((float)v.h[0], wgt, a0); a1 = fmaf((float)v.h[1], wgt, a1);
        a2 = fmaf((float)v.h[2], wgt, a2); a3 = fmaf((float)v.h[3], wgt, a3);
    }
    float* op = out + (b << 10) + tid * 4;
    atomicAdd(op + 0, a0); atomicAdd(op + 1, a1);
    atomicAdd(op + 2, a2); atomicAdd(op + 3, a3);
}

// ---------------- fallback out (f32 many) ----------------
__global__ __launch_bounds__(256)
void out_kernel(const float* __restrict__ many, const float* __restrict__ att,
                float* __restrict__ out) {
    int b = blockIdx.x >> 4, tch = blockIdx.x & 15;
    int tid = threadIdx.x;
    __shared__ float aw[128];
    if (tid < 128) aw[tid] = att[(b << 11) + tch * 128 + tid];
    __syncthreads();
    const float* mp = many + (((size_t)b * NT + tch * 128) << 10) + tid * 4;
    float ax = 0.f, ay = 0.f, az = 0.f, aww = 0.f;
    for (int t = 0; t < 128; ++t) {
        float wgt = aw[t];
        float4 v = *reinterpret_cast<const float4*>(mp + ((size_t)t << 10));
        ax = fmaf(v.x, wgt, ax); ay = fmaf(v.y, wgt, ay);
        az = fmaf(v.z, wgt, az); aww = fmaf(v.w, wgt, aww);
    }
    float* op = out + (b << 10) + tid * 4;
    atomicAdd(op + 0, ax); atomicAdd(op + 1, ay);
    atomicAdd(op + 2, az); atomicAdd(op + 3, aww);
}

extern "C" void kernel_launch(void* const* d_in, const int* in_sizes, int n_in,
                              void* d_out, int out_size, void* d_ws, size_t ws_size,
                              hipStream_t stream) {
    const float* one  = (const float*)d_in[0];   // [32][1024]
    const float* many = (const float*)d_in[1];   // [32][2048][1024]
    const float* W    = (const float*)d_in[2];   // [1024][1024]
    float* out = (float*)d_out;                  // [0,32768) result | [32768,98304) att

    size_t wtB = (size_t)ND * ND * 2;            // 2 MB
    size_t lgB = (size_t)NM * 4;                 // 256 KB
    size_t mhB = (size_t)NM * ND * 2;            // 128 MB
    _Float16* Wt    = (_Float16*)d_ws;
    float*    logits = (float*)((char*)d_ws + wtB);
    _Float16* manyh = (_Float16*)((char*)d_ws + wtB + lgB);
    float*    att   = out + NB * ND;
    bool big = ws_size >= wtB + lgB + mhB;       // harness constant -> deterministic

    (void)hipMemsetAsync(out, 0, (size_t)NB * ND * sizeof(float), stream);
    (void)hipMemsetAsync(logits, 0, (size_t)NM * sizeof(float), stream);

    wt_kernel<<<dim3(32, 32), dim3(32, 8), 0, stream>>>(W, Wt);
    if (big) {
        conv_kernel<<<2048, 256, 0, stream>>>(many, manyh);
        gemm_logits_10s<<<1024, 512, 0, stream>>>(manyh, Wt, one, logits);
    } else {
        gemm_logits<<<4096, 256, 0, stream>>>(many, Wt, one, logits);
    }
    softmax_kernel<<<NB, 256, 0, stream>>>(logits, att);
    if (big) out_kernel_h<<<NB * 16, 256, 0, stream>>>(manyh, att, out);
    else     out_kernel<<<NB * 16, 256, 0, stream>>>(many, att, out);
}

// Round 8
// 250.340 us; speedup vs baseline: 1.1035x; 1.1035x over previous
//
#include <hip/hip_runtime.h>
#include <hip/hip_bf16.h>

typedef _Float16 half8v __attribute__((ext_vector_type(8)));
typedef __fp16  fp16x2 __attribute__((ext_vector_type(2)));   // cvt_pkrtz return type
typedef float floatx4 __attribute__((ext_vector_type(4)));

#define NB 32
#define NT 2048
#define ND 1024
#define NM (NB * NT)

// global->LDS direct DMA, 16B per lane. Linear LDS dest; swizzle on the
// GLOBAL source address (rule #21).
#define GL16(g, l)                                                             \
    __builtin_amdgcn_global_load_lds(                                          \
        (const __attribute__((address_space(1))) void*)(g),                    \
        (__attribute__((address_space(3))) void*)(l), 16, 0, 0)

__device__ __forceinline__ float fast_tanh(float x) {
    x = fminf(9.0f, fmaxf(-9.0f, x));
    float e = __builtin_amdgcn_exp2f(x * 2.8853900817779268f); // e^(2x)
    return (e - 1.0f) * __builtin_amdgcn_rcpf(e + 1.0f);
}

// ---------------- W [K][N] f32  ->  Wt [N][K] fp16 ----------------
__global__ __launch_bounds__(256)
void wt_kernel(const float* __restrict__ W, _Float16* __restrict__ Wt) {
    __shared__ float tile[32][33];
    int tx = threadIdx.x, ty = threadIdx.y;
    int bx = blockIdx.x, by = blockIdx.y;
    #pragma unroll
    for (int i = 0; i < 4; ++i) {
        int y = by * 32 + ty + i * 8;
        tile[ty + i * 8][tx] = W[y * ND + bx * 32 + tx];
    }
    __syncthreads();
    #pragma unroll
    for (int i = 0; i < 4; ++i) {
        int e = bx * 32 + ty + i * 8;
        Wt[e * ND + by * 32 + tx] = (_Float16)tile[tx][ty + i * 8];
    }
}

// ---------------- many f32 -> manyh fp16 (streaming, RTN) ----------------
__global__ __launch_bounds__(256)
void conv_kernel(const float* __restrict__ many, _Float16* __restrict__ manyh) {
    size_t idx = ((size_t)blockIdx.x * 256 + threadIdx.x) * 8;
    size_t stride = (size_t)gridDim.x * 256 * 8;
    for (size_t i = idx; i < (size_t)NM * ND; i += stride) {
        float4 a = *reinterpret_cast<const float4*>(many + i);
        float4 b = *reinterpret_cast<const float4*>(many + i + 4);
        union { _Float16 h[8]; uint4 u; } o;
        o.h[0] = (_Float16)a.x; o.h[1] = (_Float16)a.y;
        o.h[2] = (_Float16)a.z; o.h[3] = (_Float16)a.w;
        o.h[4] = (_Float16)b.x; o.h[5] = (_Float16)b.y;
        o.h[6] = (_Float16)b.z; o.h[7] = (_Float16)b.w;
        *reinterpret_cast<uint4*>(manyh + i) = o.u;
    }
}

// ---- m97-faithful single-buffered GEMM + tanh + dot(one) -> logits --------
// manyh [65536][1024] fp16, Wt [1024][1024] fp16, both K-contiguous.
// 128x128 tile, BK=64, 256 thr (4 waves 2x2, wave=64x64). LDS 32 KB single
// buffer (A 16K | B 16K), 2 barriers/K-step, gl_lds staging both operands.
// Occupancy is the lever: ~4-5 blocks/CU -> implicit cross-block overlap
// (m99/m100/m114: beats explicit dbuf at 2 blocks/CU).
__global__ __launch_bounds__(256, 4)
void gemm_logits_s(const _Float16* __restrict__ manyh, const _Float16* __restrict__ Wt,
                   const float* __restrict__ one, float* __restrict__ logits) {
    __shared__ uint4 LDSQ[2048];          // 32 KB: A 16K | B 16K
    char* Ld = (char*)LDSQ;

    int bid = blockIdx.x;                  // 4096 blocks
    int j = (bid & 7) * 512 + (bid >> 3);  // XCD-chunked, bijective
    int mb = j >> 3, nb = j & 7;           // 8 consecutive j share mb -> L2 reuse
    int m0 = mb * 128, n0 = nb * 128;

    int tid = threadIdx.x;
    int lane = tid & 63, w = tid >> 6;
    int wr = w >> 1, wc = w & 1;           // 2x2 waves, each 64x64
    int l15 = lane & 15, l4 = lane >> 4;

    // staging: thread t handles chunk i*256+t: row = i*32 + (t>>3), cc = t&7;
    // source chunk = cc ^ (row&7)  (i*32 == 0 mod 8 -> key i-invariant)
    const char* aS = (const char*)manyh + ((size_t)(m0 + (tid >> 3)) << 11)
                   + (size_t)(((tid & 7) ^ ((tid >> 3) & 7)) << 4);
    const char* bS = (const char*)Wt + ((size_t)(n0 + (tid >> 3)) << 11)
                   + (size_t)(((tid & 7) ^ ((tid >> 3) & 7)) << 4);

    floatx4 acc[4][4] = {};

    #pragma unroll 1
    for (int kb = 0; kb < 1024; kb += 64) {
        #pragma unroll
        for (int i = 0; i < 4; ++i)
            GL16(aS + kb * 2 + i * 65536, Ld + i * 4096 + tid * 16);
        #pragma unroll
        for (int i = 0; i < 4; ++i)
            GL16(bS + kb * 2 + i * 65536, Ld + 16384 + i * 4096 + tid * 16);
        __syncthreads();                   // drains vmcnt -> tile resident

        #pragma unroll
        for (int ks = 0; ks < 64; ks += 32) {
            half8v af[4], bf[4];
            #pragma unroll
            for (int mi = 0; mi < 4; ++mi) {
                int r = wr * 64 + mi * 16 + l15;
                int c = (ks >> 3) + l4;
                af[mi] = *(const half8v*)(Ld + r * 128 + ((c ^ (r & 7)) << 4));
            }
            #pragma unroll
            for (int ni = 0; ni < 4; ++ni) {
                int r = wc * 64 + ni * 16 + l15;
                int c = (ks >> 3) + l4;
                bf[ni] = *(const half8v*)(Ld + 16384 + r * 128 + ((c ^ (r & 7)) << 4));
            }
            #pragma unroll
            for (int mi = 0; mi < 4; ++mi)
                #pragma unroll
                for (int ni = 0; ni < 4; ++ni)
                    acc[mi][ni] = __builtin_amdgcn_mfma_f32_16x16x32_f16(
                        af[mi], bf[ni], acc[mi][ni], 0, 0, 0);
        }
        __syncthreads();                   // reads done before next overwrite
    }

    // epilogue: tanh * one, reduce over columns, atomicAdd logits
    int bidx = m0 >> 11;
    float onev[4];
    #pragma unroll
    for (int ni = 0; ni < 4; ++ni)
        onev[ni] = one[(bidx << 10) + n0 + wc * 64 + ni * 16 + l15];

    #pragma unroll
    for (int mi = 0; mi < 4; ++mi) {
        float part[4] = {0.f, 0.f, 0.f, 0.f};
        #pragma unroll
        for (int ni = 0; ni < 4; ++ni)
            #pragma unroll
            for (int b = 0; b < 4; ++b)
                part[b] += fast_tanh(acc[mi][ni][b]) * onev[ni];
        #pragma unroll
        for (int off = 1; off < 16; off <<= 1)
            #pragma unroll
            for (int b = 0; b < 4; ++b)
                part[b] += __shfl_xor(part[b], off, 64);
        #pragma unroll
        for (int b = 0; b < 4; ++b)
            if (l15 == mi * 4 + b)
                atomicAdd(&logits[m0 + wr * 64 + mi * 16 + l4 * 4 + b], part[b]);
    }
}

// ---------------- fallback GEMM (A f32 from global, cvt at frag read) ------
__global__ __launch_bounds__(256, 2)
void gemm_logits(const float* __restrict__ many, const _Float16* __restrict__ Wt,
                 const float* __restrict__ one, float* __restrict__ logits) {
    __shared__ uint4 AsQ[2048];
    __shared__ uint4 BsQ[1024];
    char* AsB = (char*)AsQ;
    char* BsB = (char*)BsQ;

    int bid = blockIdx.x;
    int j = (bid & 7) * 512 + (bid >> 3);
    int mb = j >> 3, nb = j & 7;
    int m0 = mb * 128, n0 = nb * 128;

    int tid = threadIdx.x;
    int lane = tid & 63, w = tid >> 6;
    int wr = w >> 1, wc = w & 1;
    int l15 = lane & 15, l4 = lane >> 4;

    const char* aS = (const char*)many + ((size_t)(m0 + (tid >> 4)) << 12)
        + (size_t)(((tid & 15) ^ ((tid >> 4) & 7)) << 4);
    const char* bS = (const char*)Wt + ((size_t)(n0 + (tid >> 3)) << 11)
        + (size_t)(((tid & 7) ^ ((tid >> 3) & 7)) << 4);
    char* aD = AsB + tid * 16;
    char* bD = BsB + tid * 16;

    floatx4 acc[4][4] = {};

    for (int kb = 0; kb < 1024; kb += 64) {
        #pragma unroll
        for (int i = 0; i < 8; ++i)
            GL16(aS + kb * 4 + i * 65536, aD + i * 4096);
        #pragma unroll
        for (int i = 0; i < 4; ++i)
            GL16(bS + kb * 2 + i * 65536, bD + i * 4096);
        __syncthreads();

        #pragma unroll
        for (int ks = 0; ks < 64; ks += 32) {
            half8v af[4], bf[4];
            #pragma unroll
            for (int mi = 0; mi < 4; ++mi) {
                int r = wr * 64 + mi * 16 + l15;
                int s = l15 & 7;
                const char* base = AsB + r * 256;
                int c0 = (ks >> 2) + l4 * 2;
                float4 x = *(const float4*)(base + (size_t)((c0 ^ s) << 4));
                float4 y = *(const float4*)(base + (size_t)(((c0 + 1) ^ s) << 4));
                union { fp16x2 p[4]; half8v h; } u;
                u.p[0] = __builtin_amdgcn_cvt_pkrtz(x.x, x.y);
                u.p[1] = __builtin_amdgcn_cvt_pkrtz(x.z, x.w);
                u.p[2] = __builtin_amdgcn_cvt_pkrtz(y.x, y.y);
                u.p[3] = __builtin_amdgcn_cvt_pkrtz(y.z, y.w);
                af[mi] = u.h;
            }
            #pragma unroll
            for (int ni = 0; ni < 4; ++ni) {
                int r = wc * 64 + ni * 16 + l15;
                int s = l15 & 7;
                int c = (ks >> 3) + l4;
                bf[ni] = *(const half8v*)(BsB + r * 128 + (size_t)((c ^ s) << 4));
            }
            #pragma unroll
            for (int mi = 0; mi < 4; ++mi)
                #pragma unroll
                for (int ni = 0; ni < 4; ++ni)
                    acc[mi][ni] = __builtin_amdgcn_mfma_f32_16x16x32_f16(
                        af[mi], bf[ni], acc[mi][ni], 0, 0, 0);
        }
        __syncthreads();
    }

    int bidx = m0 >> 11;
    float onev[4];
    #pragma unroll
    for (int ni = 0; ni < 4; ++ni)
        onev[ni] = one[(bidx << 10) + n0 + wc * 64 + ni * 16 + l15];

    #pragma unroll
    for (int mi = 0; mi < 4; ++mi) {
        float part[4] = {0.f, 0.f, 0.f, 0.f};
        #pragma unroll
        for (int ni = 0; ni < 4; ++ni)
            #pragma unroll
            for (int b = 0; b < 4; ++b)
                part[b] += fast_tanh(acc[mi][ni][b]) * onev[ni];
        #pragma unroll
        for (int off = 1; off < 16; off <<= 1)
            #pragma unroll
            for (int b = 0; b < 4; ++b)
                part[b] += __shfl_xor(part[b], off, 64);
        #pragma unroll
        for (int b = 0; b < 4; ++b)
            if (l15 == mi * 4 + b)
                atomicAdd(&logits[m0 + wr * 64 + mi * 16 + l4 * 4 + b], part[b]);
    }
}

// ---------------- softmax over T per batch ----------------
__global__ __launch_bounds__(256)
void softmax_kernel(const float* __restrict__ logits, float* __restrict__ att) {
    int b = blockIdx.x, tid = threadIdx.x;
    const float* lr = logits + (b << 11);
    float lv[8];
    float mx = -1e30f;
    #pragma unroll
    for (int i = 0; i < 8; ++i) { lv[i] = lr[tid + (i << 8)]; mx = fmaxf(mx, lv[i]); }
    #pragma unroll
    for (int off = 1; off < 64; off <<= 1) mx = fmaxf(mx, __shfl_xor(mx, off, 64));
    __shared__ float redm[4];
    __shared__ float reds[4];
    int wv = tid >> 6;
    if ((tid & 63) == 0) redm[wv] = mx;
    __syncthreads();
    mx = fmaxf(fmaxf(redm[0], redm[1]), fmaxf(redm[2], redm[3]));
    float s = 0.f;
    #pragma unroll
    for (int i = 0; i < 8; ++i) { lv[i] = expf(lv[i] - mx); s += lv[i]; }
    #pragma unroll
    for (int off = 1; off < 64; off <<= 1) s += __shfl_xor(s, off, 64);
    if ((tid & 63) == 0) reds[wv] = s;
    __syncthreads();
    s = reds[0] + reds[1] + reds[2] + reds[3];
    float inv = 1.0f / (s + 1e-7f);
    #pragma unroll
    for (int i = 0; i < 8; ++i) att[(b << 11) + tid + (i << 8)] = lv[i] * inv;
}

// ------- result[b][d] = sum_t many[b][t][d] * att[b][t] (fp16 input) -------
__global__ __launch_bounds__(256)
void out_kernel_h(const _Float16* __restrict__ manyh, const float* __restrict__ att,
                  float* __restrict__ out) {
    int b = blockIdx.x >> 4, tch = blockIdx.x & 15;
    int tid = threadIdx.x;
    __shared__ float aw[128];
    if (tid < 128) aw[tid] = att[(b << 11) + tch * 128 + tid];
    __syncthreads();
    const _Float16* mp = manyh + (((size_t)b * NT + tch * 128) << 10) + tid * 4;
    float a0 = 0.f, a1 = 0.f, a2 = 0.f, a3 = 0.f;
    for (int t = 0; t < 128; ++t) {
        float wgt = aw[t];
        union { _Float16 h[4]; uint2 u; } v;
        v.u = *reinterpret_cast<const uint2*>(mp + ((size_t)t << 10));
        a0 = fmaf((float)v.h[0], wgt, a0); a1 = fmaf((float)v.h[1], wgt, a1);
        a2 = fmaf((float)v.h[2], wgt, a2); a3 = fmaf((float)v.h[3], wgt, a3);
    }
    float* op = out + (b << 10) + tid * 4;
    atomicAdd(op + 0, a0); atomicAdd(op + 1, a1);
    atomicAdd(op + 2, a2); atomicAdd(op + 3, a3);
}

// ---------------- fallback out (f32 many) ----------------
__global__ __launch_bounds__(256)
void out_kernel(const float* __restrict__ many, const float* __restrict__ att,
                float* __restrict__ out) {
    int b = blockIdx.x >> 4, tch = blockIdx.x & 15;
    int tid = threadIdx.x;
    __shared__ float aw[128];
    if (tid < 128) aw[tid] = att[(b << 11) + tch * 128 + tid];
    __syncthreads();
    const float* mp = many + (((size_t)b * NT + tch * 128) << 10) + tid * 4;
    float ax = 0.f, ay = 0.f, az = 0.f, aww = 0.f;
    for (int t = 0; t < 128; ++t) {
        float wgt = aw[t];
        float4 v = *reinterpret_cast<const float4*>(mp + ((size_t)t << 10));
        ax = fmaf(v.x, wgt, ax); ay = fmaf(v.y, wgt, ay);
        az = fmaf(v.z, wgt, az); aww = fmaf(v.w, wgt, aww);
    }
    float* op = out + (b << 10) + tid * 4;
    atomicAdd(op + 0, ax); atomicAdd(op + 1, ay);
    atomicAdd(op + 2, az); atomicAdd(op + 3, aww);
}

extern "C" void kernel_launch(void* const* d_in, const int* in_sizes, int n_in,
                              void* d_out, int out_size, void* d_ws, size_t ws_size,
                              hipStream_t stream) {
    const float* one  = (const float*)d_in[0];   // [32][1024]
    const float* many = (const float*)d_in[1];   // [32][2048][1024]
    const float* W    = (const float*)d_in[2];   // [1024][1024]
    float* out = (float*)d_out;                  // [0,32768) result | [32768,98304) att

    size_t wtB = (size_t)ND * ND * 2;            // 2 MB
    size_t lgB = (size_t)NM * 4;                 // 256 KB
    size_t mhB = (size_t)NM * ND * 2;            // 128 MB
    _Float16* Wt    = (_Float16*)d_ws;
    float*    logits = (float*)((char*)d_ws + wtB);
    _Float16* manyh = (_Float16*)((char*)d_ws + wtB + lgB);
    float*    att   = out + NB * ND;
    bool big = ws_size >= wtB + lgB + mhB;       // harness constant -> deterministic

    (void)hipMemsetAsync(out, 0, (size_t)NB * ND * sizeof(float), stream);
    (void)hipMemsetAsync(logits, 0, (size_t)NM * sizeof(float), stream);

    wt_kernel<<<dim3(32, 32), dim3(32, 8), 0, stream>>>(W, Wt);
    if (big) {
        conv_kernel<<<2048, 256, 0, stream>>>(many, manyh);
        gemm_logits_s<<<4096, 256, 0, stream>>>(manyh, Wt, one, logits);
    } else {
        gemm_logits<<<4096, 256, 0, stream>>>(many, Wt, one, logits);
    }
    softmax_kernel<<<NB, 256, 0, stream>>>(logits, att);
    if (big) out_kernel_h<<<NB * 16, 256, 0, stream>>>(manyh, att, out);
    else     out_kernel<<<NB * 16, 256, 0, stream>>>(many, att, out);
}

// Round 9
// 240.900 us; speedup vs baseline: 1.1468x; 1.0392x over previous
//
#include <hip/hip_runtime.h>
#include <hip/hip_bf16.h>

typedef _Float16 half8v __attribute__((ext_vector_type(8)));
typedef __fp16  fp16x2 __attribute__((ext_vector_type(2)));   // cvt_pkrtz return type
typedef float floatx4 __attribute__((ext_vector_type(4)));

#define NB 32
#define NT 2048
#define ND 1024
#define NM (NB * NT)

// global->LDS direct DMA, 16B per lane. Linear LDS dest; swizzle on the
// GLOBAL source address (rule #21).
#define GL16(g, l)                                                             \
    __builtin_amdgcn_global_load_lds(                                          \
        (const __attribute__((address_space(1))) void*)(g),                    \
        (__attribute__((address_space(3))) void*)(l), 16, 0, 0)

__device__ __forceinline__ float fast_tanh(float x) {
    x = fminf(9.0f, fmaxf(-9.0f, x));
    float e = __builtin_amdgcn_exp2f(x * 2.8853900817779268f); // e^(2x)
    return (e - 1.0f) * __builtin_amdgcn_rcpf(e + 1.0f);
}

// ---------------- zero out + logits (replaces slow fillBuffer) ----------------
__global__ __launch_bounds__(256)
void zero_kernel(float* __restrict__ out, float* __restrict__ logits) {
    int i = blockIdx.x * 256 + threadIdx.x;      // grid 256 -> 65536 threads
    logits[i] = 0.f;
    if (i < NB * ND) out[i] = 0.f;
}

// ---------------- W [K][N] f32  ->  Wt [N][K] fp16 ----------------
__global__ __launch_bounds__(256)
void wt_kernel(const float* __restrict__ W, _Float16* __restrict__ Wt) {
    __shared__ float tile[32][33];
    int tx = threadIdx.x, ty = threadIdx.y;
    int bx = blockIdx.x, by = blockIdx.y;
    #pragma unroll
    for (int i = 0; i < 4; ++i) {
        int y = by * 32 + ty + i * 8;
        tile[ty + i * 8][tx] = W[y * ND + bx * 32 + tx];
    }
    __syncthreads();
    #pragma unroll
    for (int i = 0; i < 4; ++i) {
        int e = bx * 32 + ty + i * 8;
        Wt[e * ND + by * 32 + tx] = (_Float16)tile[tx][ty + i * 8];
    }
}

// ---- GEMM + tanh + dot(one) -> logits. A = many f32 staged via gl_lds, ----
// ---- converted at frag read; B = Wt fp16. 128x128 tile, BK=64, 48 KB LDS --
// ---- single buffer, 2 barriers/K-step, XCD-chunked swizzle, occupancy 3. --
__global__ __launch_bounds__(256, 3)
void gemm_logits(const float* __restrict__ many, const _Float16* __restrict__ Wt,
                 const float* __restrict__ one, float* __restrict__ logits) {
    __shared__ uint4 AsQ[2048];   // 32 KB: A tile f32 [128][64], src-swizzled
    __shared__ uint4 BsQ[1024];   // 16 KB: B tile f16 [128][64], src-swizzled
    char* AsB = (char*)AsQ;
    char* BsB = (char*)BsQ;

    int bid = blockIdx.x;
    int j = (bid & 7) * 512 + (bid >> 3);  // XCD-chunked, bijective (4096%8==0)
    int mb = j >> 3, nb = j & 7;           // 8 consecutive j share mb -> L2 reuse
    int m0 = mb * 128, n0 = nb * 128;

    int tid = threadIdx.x;
    int lane = tid & 63, w = tid >> 6;
    int wr = w >> 1, wc = w & 1;           // 2x2 waves, each 64x64
    int l15 = lane & 15, l4 = lane >> 4;

    // A: 2048 16B-chunks/tile; thread handles chunk i*256+tid (i=0..7):
    //    row = i*16 + (tid>>4), cc = tid&15; src chunk = cc ^ (row&7).
    const char* aS = (const char*)many + ((size_t)(m0 + (tid >> 4)) << 12)
        + (size_t)(((tid & 15) ^ ((tid >> 4) & 7)) << 4);
    // B: 1024 chunks; row = i*32 + (tid>>3), cc = tid&7; src chunk = cc ^ (row&7).
    const char* bS = (const char*)Wt + ((size_t)(n0 + (tid >> 3)) << 11)
        + (size_t)(((tid & 7) ^ ((tid >> 3) & 7)) << 4);
    char* aD = AsB + tid * 16;
    char* bD = BsB + tid * 16;

    floatx4 acc[4][4] = {};

    #pragma unroll 1
    for (int kb = 0; kb < 1024; kb += 64) {
        #pragma unroll
        for (int i = 0; i < 8; ++i)
            GL16(aS + kb * 4 + i * 65536, aD + i * 4096);
        #pragma unroll
        for (int i = 0; i < 4; ++i)
            GL16(bS + kb * 2 + i * 65536, bD + i * 4096);
        __syncthreads();

        #pragma unroll
        for (int ks = 0; ks < 64; ks += 32) {
            half8v af[4], bf[4];
            #pragma unroll
            for (int mi = 0; mi < 4; ++mi) {
                int r = wr * 64 + mi * 16 + l15;
                int s = l15 & 7;
                const char* base = AsB + r * 256;
                int c0 = (ks >> 2) + l4 * 2;
                float4 x = *(const float4*)(base + (size_t)((c0 ^ s) << 4));
                float4 y = *(const float4*)(base + (size_t)(((c0 + 1) ^ s) << 4));
                union { fp16x2 p[4]; half8v h; } u;
                u.p[0] = __builtin_amdgcn_cvt_pkrtz(x.x, x.y);
                u.p[1] = __builtin_amdgcn_cvt_pkrtz(x.z, x.w);
                u.p[2] = __builtin_amdgcn_cvt_pkrtz(y.x, y.y);
                u.p[3] = __builtin_amdgcn_cvt_pkrtz(y.z, y.w);
                af[mi] = u.h;
            }
            #pragma unroll
            for (int ni = 0; ni < 4; ++ni) {
                int r = wc * 64 + ni * 16 + l15;
                int s = l15 & 7;
                int c = (ks >> 3) + l4;
                bf[ni] = *(const half8v*)(BsB + r * 128 + (size_t)((c ^ s) << 4));
            }
            #pragma unroll
            for (int mi = 0; mi < 4; ++mi)
                #pragma unroll
                for (int ni = 0; ni < 4; ++ni)
                    acc[mi][ni] = __builtin_amdgcn_mfma_f32_16x16x32_f16(
                        af[mi], bf[ni], acc[mi][ni], 0, 0, 0);
        }
        __syncthreads();
    }

    // epilogue: tanh * one, reduce over columns, atomicAdd logits
    int bidx = m0 >> 11;
    float onev[4];
    #pragma unroll
    for (int ni = 0; ni < 4; ++ni)
        onev[ni] = one[(bidx << 10) + n0 + wc * 64 + ni * 16 + l15];

    #pragma unroll
    for (int mi = 0; mi < 4; ++mi) {
        float part[4] = {0.f, 0.f, 0.f, 0.f};
        #pragma unroll
        for (int ni = 0; ni < 4; ++ni)
            #pragma unroll
            for (int b = 0; b < 4; ++b)
                part[b] += fast_tanh(acc[mi][ni][b]) * onev[ni];
        #pragma unroll
        for (int off = 1; off < 16; off <<= 1)
            #pragma unroll
            for (int b = 0; b < 4; ++b)
                part[b] += __shfl_xor(part[b], off, 64);
        #pragma unroll
        for (int b = 0; b < 4; ++b)
            if (l15 == mi * 4 + b)
                atomicAdd(&logits[m0 + wr * 64 + mi * 16 + l4 * 4 + b], part[b]);
    }
}

// ---------------- softmax over T per batch ----------------
__global__ __launch_bounds__(256)
void softmax_kernel(const float* __restrict__ logits, float* __restrict__ att) {
    int b = blockIdx.x, tid = threadIdx.x;
    const float* lr = logits + (b << 11);
    float lv[8];
    float mx = -1e30f;
    #pragma unroll
    for (int i = 0; i < 8; ++i) { lv[i] = lr[tid + (i << 8)]; mx = fmaxf(mx, lv[i]); }
    #pragma unroll
    for (int off = 1; off < 64; off <<= 1) mx = fmaxf(mx, __shfl_xor(mx, off, 64));
    __shared__ float redm[4];
    __shared__ float reds[4];
    int wv = tid >> 6;
    if ((tid & 63) == 0) redm[wv] = mx;
    __syncthreads();
    mx = fmaxf(fmaxf(redm[0], redm[1]), fmaxf(redm[2], redm[3]));
    float s = 0.f;
    #pragma unroll
    for (int i = 0; i < 8; ++i) { lv[i] = expf(lv[i] - mx); s += lv[i]; }
    #pragma unroll
    for (int off = 1; off < 64; off <<= 1) s += __shfl_xor(s, off, 64);
    if ((tid & 63) == 0) reds[wv] = s;
    __syncthreads();
    s = reds[0] + reds[1] + reds[2] + reds[3];
    float inv = 1.0f / (s + 1e-7f);
    #pragma unroll
    for (int i = 0; i < 8; ++i) att[(b << 11) + tid + (i << 8)] = lv[i] * inv;
}

// ---------------- result[b][d] = sum_t many[b][t][d] * att[b][t] ----------------
__global__ __launch_bounds__(256)
void out_kernel(const float* __restrict__ many, const float* __restrict__ att,
                float* __restrict__ out) {
    int b = blockIdx.x >> 4, tch = blockIdx.x & 15;   // 16 t-chunks of 128
    int tid = threadIdx.x;
    __shared__ float aw[128];
    if (tid < 128) aw[tid] = att[(b << 11) + tch * 128 + tid];
    __syncthreads();
    const float* mp = many + (((size_t)b * NT + tch * 128) << 10) + tid * 4;
    float ax = 0.f, ay = 0.f, az = 0.f, aww = 0.f;
    for (int t = 0; t < 128; ++t) {
        float wgt = aw[t];
        float4 v = *reinterpret_cast<const float4*>(mp + ((size_t)t << 10));
        ax = fmaf(v.x, wgt, ax); ay = fmaf(v.y, wgt, ay);
        az = fmaf(v.z, wgt, az); aww = fmaf(v.w, wgt, aww);
    }
    float* op = out + (b << 10) + tid * 4;
    atomicAdd(op + 0, ax); atomicAdd(op + 1, ay);
    atomicAdd(op + 2, az); atomicAdd(op + 3, aww);
}

extern "C" void kernel_launch(void* const* d_in, const int* in_sizes, int n_in,
                              void* d_out, int out_size, void* d_ws, size_t ws_size,
                              hipStream_t stream) {
    const float* one  = (const float*)d_in[0];   // [32][1024]
    const float* many = (const float*)d_in[1];   // [32][2048][1024]
    const float* W    = (const float*)d_in[2];   // [1024][1024]
    float* out = (float*)d_out;                  // [0,32768) result | [32768,98304) att

    _Float16* Wt     = (_Float16*)d_ws;                          // 2 MB
    float*    logits = (float*)((char*)d_ws + (size_t)ND * ND * 2);  // 256 KB
    float*    att    = out + NB * ND;

    zero_kernel<<<256, 256, 0, stream>>>(out, logits);
    wt_kernel<<<dim3(32, 32), dim3(32, 8), 0, stream>>>(W, Wt);
    gemm_logits<<<4096, 256, 0, stream>>>(many, Wt, one, logits);
    softmax_kernel<<<NB, 256, 0, stream>>>(logits, att);
    out_kernel<<<NB * 16, 256, 0, stream>>>(many, att, out);
}